// Round 5
// baseline (240.247 us; speedup 1.0000x reference)
//
#include <hip/hip_runtime.h>
#include <hip/hip_bf16.h>
#include <math.h>

#define BB 4
#define TT 1024
#define FF 1024
#define DIM 1024
#define NH 16
#define HD 64
#define MROWS (BB * TT)   // 4096
#define FB (FF / 64)      // 16 uint64 mask words per row

typedef __attribute__((ext_vector_type(8))) short short8;
typedef __attribute__((ext_vector_type(4))) float f32x4;
typedef __hip_bfloat16 bf16;

__device__ __forceinline__ void async_copy16(const void* g, void* l) {
    __builtin_amdgcn_global_load_lds((const __attribute__((address_space(1))) void*)g,
                                     (__attribute__((address_space(3))) void*)l,
                                     16, 0, 0);
}

// ---------------------------------------------------------------------------
// Fused f32->bf16 convert (segments 0..5) + mask bit-pack (tail blocks).
// ---------------------------------------------------------------------------
struct ConvArgs {
    const float* src[6];
    bf16* dst[6];
    int nvec[6];
    int blk_end[6];
    const int* mask;
    unsigned long long* Mb;
};

__global__ __launch_bounds__(256) void convert_pack(ConvArgs a) {
    int bx = blockIdx.x;
    if (bx >= a.blk_end[5]) {
        const int lane = threadIdx.x & 63;
        const int waveId = (bx - a.blk_end[5]) * 4 + (threadIdx.x >> 6);
#pragma unroll
        for (int it = 0; it < 16; ++it) {
            int c = waveId * 16 + it;
            int v = a.mask[(size_t)c * 64 + lane];
            unsigned long long bits = __ballot(v != 0);
            if (lane == 0) a.Mb[c] = bits;
        }
        return;
    }
    int seg = 0;
#pragma unroll
    for (int k = 0; k < 5; ++k) if (bx >= a.blk_end[k]) seg = k + 1;
    int b0 = seg ? a.blk_end[seg - 1] : 0;
    int idx = (bx - b0) * 256 + threadIdx.x;
    if (idx >= a.nvec[seg]) return;
    float4 v = ((const float4*)a.src[seg])[idx];
    union { bf16 t[4]; ushort4 u; } o;
    o.t[0] = __float2bfloat16(v.x);
    o.t[1] = __float2bfloat16(v.y);
    o.t[2] = __float2bfloat16(v.z);
    o.t[3] = __float2bfloat16(v.w);
    *(ushort4*)(a.dst[seg] + 4 * (size_t)idx) = o.u;
}

// ---------------------------------------------------------------------------
// Fused Q/K/Vt projection GEMMs. grid (8,32,3). 128x128 tile, BK=64.
// XCD-aware block remap: lin&7 selects XCD-resident m-slice (or n-slice for
// the transposed Vt op) so per-XCD L2 working set = 1MB A-slice + 2MB W.
// ---------------------------------------------------------------------------
#define BK 64

struct QkvArgs {
    const bf16* A[3]; const bf16* W[3]; const float* bias[3]; bf16* C[3];
    int N[3]; int biasRow[3];
};

__global__ __launch_bounds__(256) void gemm_qkv(QkvArgs q) {
    __shared__ bf16 smem[128 * 132];
    bf16* As = smem;
    bf16* Bs = smem + 128 * BK;

    const int op = blockIdx.z;
    const bf16* A = q.A[op];
    const bf16* W = q.W[op];
    const float* bias = q.bias[op];
    bf16* C = q.C[op];
    const int N = q.N[op];
    const int brow = q.biasRow[op];

    // XCD-aware remap: hardware round-robins linear block id over 8 XCDs.
    const int lin = blockIdx.x + 8 * blockIdx.y;   // 0..255
    const int xcd = lin & 7;
    const int t   = lin >> 3;                      // 0..31
    int m0, n0;
    if (brow) {  // Vt op: C is 1024x4096 (mb=8, nb=32); A=Wk (2MB) full per XCD
        m0 = (((t & 7) + xcd) & 7) * 128;
        n0 = (xcd * 4 + (t >> 3)) * 128;
    } else {     // Q/K: mb=32, nb=8; W (2MB) full per XCD, A-slice 1MB
        m0 = (xcd * 4 + (t >> 3)) * 128;
        n0 = (((t & 7) + xcd) & 7) * 128;
    }

    const int tid  = threadIdx.x;
    const int lane = tid & 63;
    const int wave = tid >> 6;
    const int quad = lane >> 4;
    const int l16  = lane & 15;
    const int wm = wave & 1;
    const int wn = wave >> 1;
    const int wbase = tid & ~63;

    f32x4 acc[4][4] = {};

    for (int k0 = 0; k0 < DIM; k0 += BK) {
#pragma unroll
        for (int j = 0; j < 4; ++j) {
            int slot = j * 256 + tid;
            int r = slot >> 3;
            int g = (slot & 7) ^ (r & 7);
            async_copy16(A + (size_t)(m0 + r) * DIM + k0 + g * 8,
                         As + (size_t)(j * 256 + wbase) * 8);
            async_copy16(W + (size_t)(n0 + r) * DIM + k0 + g * 8,
                         Bs + (size_t)(j * 256 + wbase) * 8);
        }
        __syncthreads();

#pragma unroll
        for (int kk = 0; kk < 2; ++kk) {
            short8 a[4], b[4];
#pragma unroll
            for (int mi = 0; mi < 4; ++mi) {
                int r = wm * 64 + mi * 16 + l16;
                int p = (kk * 4 + quad) ^ (r & 7);
                a[mi] = *(const short8*)(As + r * BK + p * 8);
            }
#pragma unroll
            for (int ni = 0; ni < 4; ++ni) {
                int r = wn * 64 + ni * 16 + l16;
                int p = (kk * 4 + quad) ^ (r & 7);
                b[ni] = *(const short8*)(Bs + r * BK + p * 8);
            }
#pragma unroll
            for (int mi = 0; mi < 4; ++mi)
#pragma unroll
                for (int ni = 0; ni < 4; ++ni)
                    acc[mi][ni] = __builtin_amdgcn_mfma_f32_16x16x32_bf16(
                        a[mi], b[ni], acc[mi][ni], 0, 0, 0);
        }
        __syncthreads();
    }

    bf16* Cs = smem;   // 128 x 132
#pragma unroll
    for (int ni = 0; ni < 4; ++ni) {
        const int nl = wn * 64 + ni * 16 + l16;
        float bcol = brow ? 0.0f : bias[n0 + nl];
#pragma unroll
        for (int mi = 0; mi < 4; ++mi)
#pragma unroll
            for (int i = 0; i < 4; ++i) {
                const int ml = wm * 64 + mi * 16 + quad * 4 + i;
                float v = acc[mi][ni][i] + (brow ? bias[m0 + ml] : bcol);
                Cs[ml * 132 + nl] = __float2bfloat16(v);
            }
    }
    __syncthreads();
#pragma unroll
    for (int j = 0; j < 8; ++j) {
        int slot = j * 256 + tid;
        int rr = slot >> 4, cc = slot & 15;
        short8 v = *(const short8*)(Cs + rr * 132 + cc * 8);
        *(short8*)(C + (size_t)(m0 + rr) * N + n0 + cc * 8) = v;
    }
}

// ---------------------------------------------------------------------------
// O-projection GEMM: out f32 = A bf16 @ Wo^T + bo. 128x64 tile, BK=64,
// grid (16,32) = 512 blocks, XCD remap (A-slice 1MB + Wo 2MB per XCD).
// ---------------------------------------------------------------------------
__global__ __launch_bounds__(256) void gemm_o(
    const bf16* __restrict__ A, const bf16* __restrict__ W,
    const float* __restrict__ bias, float* __restrict__ C)
{
    __shared__ float smemf[128 * 66];
    bf16* As = (bf16*)smemf;
    bf16* Bs = As + 128 * BK;

    const int lin = blockIdx.x + 16 * blockIdx.y;  // 0..511
    const int xcd = lin & 7;
    const int t   = lin >> 3;                      // 0..63
    const int m0 = (xcd * 4 + (t >> 4)) * 128;
    const int n0 = (((t & 15) + 2 * xcd) & 15) * 64;

    const int tid  = threadIdx.x;
    const int lane = tid & 63;
    const int wave = tid >> 6;
    const int quad = lane >> 4;
    const int l16  = lane & 15;
    const int wm = wave & 1;
    const int wn = wave >> 1;
    const int wbase = tid & ~63;

    f32x4 acc[4][2] = {};

    for (int k0 = 0; k0 < DIM; k0 += BK) {
#pragma unroll
        for (int j = 0; j < 4; ++j) {
            int slot = j * 256 + tid;
            int r = slot >> 3;
            int g = (slot & 7) ^ (r & 7);
            async_copy16(A + (size_t)(m0 + r) * DIM + k0 + g * 8,
                         As + (size_t)(j * 256 + wbase) * 8);
        }
#pragma unroll
        for (int j = 0; j < 2; ++j) {
            int slot = j * 256 + tid;
            int r = slot >> 3;
            int g = (slot & 7) ^ (r & 7);
            async_copy16(W + (size_t)(n0 + r) * DIM + k0 + g * 8,
                         Bs + (size_t)(j * 256 + wbase) * 8);
        }
        __syncthreads();

#pragma unroll
        for (int kk = 0; kk < 2; ++kk) {
            short8 a[4], b[2];
#pragma unroll
            for (int mi = 0; mi < 4; ++mi) {
                int r = wm * 64 + mi * 16 + l16;
                int p = (kk * 4 + quad) ^ (r & 7);
                a[mi] = *(const short8*)(As + r * BK + p * 8);
            }
#pragma unroll
            for (int ni = 0; ni < 2; ++ni) {
                int r = wn * 32 + ni * 16 + l16;
                int p = (kk * 4 + quad) ^ (r & 7);
                b[ni] = *(const short8*)(Bs + r * BK + p * 8);
            }
#pragma unroll
            for (int mi = 0; mi < 4; ++mi)
#pragma unroll
                for (int ni = 0; ni < 2; ++ni)
                    acc[mi][ni] = __builtin_amdgcn_mfma_f32_16x16x32_bf16(
                        a[mi], b[ni], acc[mi][ni], 0, 0, 0);
        }
        __syncthreads();
    }

    float* Cs = smemf;  // 128 x 66
#pragma unroll
    for (int ni = 0; ni < 2; ++ni) {
        const int nl = wn * 32 + ni * 16 + l16;
        const float bcol = bias[n0 + nl];
#pragma unroll
        for (int mi = 0; mi < 4; ++mi)
#pragma unroll
            for (int i = 0; i < 4; ++i) {
                const int ml = wm * 64 + mi * 16 + quad * 4 + i;
                Cs[ml * 66 + nl] = acc[mi][ni][i] + bcol;
            }
    }
    __syncthreads();
#pragma unroll
    for (int j = 0; j < 8; ++j) {
        int slot = j * 256 + tid;
        int rr = slot >> 4, cc = slot & 15;
        float4 v = *(const float4*)(Cs + rr * 66 + cc * 4);
        *(float4*)(C + (size_t)(m0 + rr) * DIM + n0 + cc * 4) = v;
    }
}

// ---------------------------------------------------------------------------
// MFMA flash attention, no-max softmax, f-chunk 128 (8 barrier iters, 32
// MFMA/wave/iter).  XCD remap: each XCD owns 8 whole (b,h) groups so K/V are
// fetched once per XCD.  Og aliases Qg (block reads its Q before writing O).
// ---------------------------------------------------------------------------
__global__ __launch_bounds__(256) void attn_kernel(
    const bf16* Qg, const bf16* __restrict__ Kg, const bf16* __restrict__ Vtg,
    const unsigned long long* __restrict__ Mbits, bf16* Og)
{
    __shared__ bf16 Ks[128 * 64];   // [f][d]
    __shared__ bf16 Vts[64 * 128];  // [d][f]
    __shared__ bf16 Ps[64 * 136];   // [r][f] padded

    const int tid  = threadIdx.x;
    const int lane = tid & 63;
    const int wave = tid >> 6;
    const int quad = lane >> 4;
    const int l16  = lane & 15;

    // XCD remap: 1024 blocks -> xcd owns bh groups xcd*8..xcd*8+7
    const int lin = blockIdx.x + 16 * (blockIdx.y + 16 * blockIdx.z);
    const int xcd = lin & 7;
    const int t   = lin >> 3;            // 0..127
    const int bh  = xcd * 8 + (t >> 4);  // 0..63
    const int b   = bh >> 4;
    const int h   = bh & 15;
    const int t0  = (t & 15) * 64;

    const size_t qrow0 = (size_t)b * TT + t0;
    const size_t krow0 = (size_t)b * FF;
    const int wbase = tid & ~63;

    const bf16* qptr = Qg + (qrow0 + wave * 16 + l16) * DIM + h * HD;
    short8 qa0 = *(const short8*)(qptr + quad * 8);
    short8 qa1 = *(const short8*)(qptr + 32 + quad * 8);

    float lrow[4] = {0.f, 0.f, 0.f, 0.f};
    f32x4 oacc[4] = {};

    for (int f0 = 0; f0 < FF; f0 += 128) {
        // stage K chunk 128x64 and Vt chunk 64x128 (swizzled)
#pragma unroll
        for (int j = 0; j < 4; ++j) {
            int slot = j * 256 + tid;
            int rk = slot >> 3;
            int gk = (slot & 7) ^ (rk & 7);
            async_copy16(Kg + (krow0 + f0 + rk) * DIM + h * HD + gk * 8,
                         Ks + (size_t)(j * 256 + wbase) * 8);
            int rv = slot >> 4;
            int gv = (slot & 15) ^ (rv & 15);
            async_copy16(Vtg + (size_t)(h * HD + rv) * MROWS + b * FF + f0 + gv * 8,
                         Vts + (size_t)(j * 256 + wbase) * 8);
        }
        __syncthreads();

        // S = Q @ K^T : 16 rows x 128 cols per wave
        f32x4 sacc[8] = {};
#pragma unroll
        for (int nt = 0; nt < 8; ++nt) {
            int r = nt * 16 + l16;
            short8 kb0 = *(const short8*)(Ks + r * 64 + ((quad       ^ (r & 7)) * 8));
            short8 kb1 = *(const short8*)(Ks + r * 64 + (((quad + 4) ^ (r & 7)) * 8));
            sacc[nt] = __builtin_amdgcn_mfma_f32_16x16x32_bf16(qa0, kb0, sacc[nt], 0, 0, 0);
            sacc[nt] = __builtin_amdgcn_mfma_f32_16x16x32_bf16(qa1, kb1, sacc[nt], 0, 0, 0);
        }

        // mask bits + exp + P to LDS + l accumulate (2 mask words per row)
#pragma unroll
        for (int i = 0; i < 4; ++i) {
            const int prow = wave * 16 + quad * 4 + i;
#pragma unroll
            for (int half = 0; half < 2; ++half) {
                unsigned long long m64 = Mbits[(qrow0 + prow) * FB + (f0 >> 6) + half];
                unsigned long long sh = m64 >> l16;
                unsigned lo = (unsigned)sh, hi = (unsigned)(sh >> 32);
                const int sb = half * 4;
                float p0 = (lo & 1u)         ? __expf(sacc[sb + 0][i] * 0.125f) : 0.f;
                float p1 = ((lo >> 16) & 1u) ? __expf(sacc[sb + 1][i] * 0.125f) : 0.f;
                float p2 = (hi & 1u)         ? __expf(sacc[sb + 2][i] * 0.125f) : 0.f;
                float p3 = ((hi >> 16) & 1u) ? __expf(sacc[sb + 3][i] * 0.125f) : 0.f;
                lrow[i] += p0 + p1 + p2 + p3;
                Ps[prow * 136 + half * 64 +  0 + l16] = __float2bfloat16(p0);
                Ps[prow * 136 + half * 64 + 16 + l16] = __float2bfloat16(p1);
                Ps[prow * 136 + half * 64 + 32 + l16] = __float2bfloat16(p2);
                Ps[prow * 136 + half * 64 + 48 + l16] = __float2bfloat16(p3);
            }
        }

        // O += P @ V  (own-wave Ps rows; no barrier needed before reads)
        short8 pa[4];
#pragma unroll
        for (int kf = 0; kf < 4; ++kf)
            pa[kf] = *(const short8*)(Ps + (wave * 16 + l16) * 136 + kf * 32 + quad * 8);
#pragma unroll
        for (int nt = 0; nt < 4; ++nt) {
            int rd = nt * 16 + l16;
#pragma unroll
            for (int kf = 0; kf < 4; ++kf) {
                int g = (kf * 4 + quad) ^ (rd & 15);
                short8 vb = *(const short8*)(Vts + rd * 128 + g * 8);
                oacc[nt] = __builtin_amdgcn_mfma_f32_16x16x32_bf16(pa[kf], vb, oacc[nt], 0, 0, 0);
            }
        }
        __syncthreads();   // protect Ks/Vts before next staging
    }

    // final l reduction + normalize + coalesced store via Ps
#pragma unroll
    for (int i = 0; i < 4; ++i) {
        float l = lrow[i];
        l += __shfl_xor(l, 1);
        l += __shfl_xor(l, 2);
        l += __shfl_xor(l, 4);
        l += __shfl_xor(l, 8);
        float inv = 1.0f / l;
        const int prow = wave * 16 + quad * 4 + i;
#pragma unroll
        for (int nt = 0; nt < 4; ++nt)
            Ps[prow * 136 + nt * 16 + l16] = __float2bfloat16(oacc[nt][i] * inv);
    }
    __syncthreads();
#pragma unroll
    for (int j = 0; j < 2; ++j) {
        int s = j * 256 + tid;
        int rr = s >> 3, off = (s & 7) * 8;
        short8 v = *(const short8*)(Ps + rr * 136 + off);
        *(short8*)(Og + (qrow0 + rr) * DIM + h * HD + off) = v;
    }
}

// ---------------------------------------------------------------------------
extern "C" void kernel_launch(void* const* d_in, const int* in_sizes, int n_in,
                              void* d_out, int out_size, void* d_ws, size_t ws_size,
                              hipStream_t stream) {
    const float* X_to   = (const float*)d_in[0];
    const float* X_from = (const float*)d_in[1];
    const int*   mask   = (const int*)  d_in[2];
    const float* Wq     = (const float*)d_in[3];
    const float* bq     = (const float*)d_in[4];
    const float* Wk     = (const float*)d_in[5];
    const float* bk     = (const float*)d_in[6];
    const float* Wv     = (const float*)d_in[7];
    const float* bv     = (const float*)d_in[8];
    const float* Wo     = (const float*)d_in[9];
    const float* bo     = (const float*)d_in[10];
    float* out = (float*)d_out;

    char* ws = (char*)d_ws;
    bf16* Xt16 = (bf16*)(ws);
    bf16* Xf16 = (bf16*)(ws + (8u  << 20));
    bf16* Wq16 = (bf16*)(ws + (16u << 20));
    bf16* Wv16 = (bf16*)(ws + (18u << 20));
    bf16* Wk16 = (bf16*)(ws + (20u << 20));
    bf16* Wo16 = (bf16*)(ws + (22u << 20));
    bf16* Q16  = (bf16*)(ws + (24u << 20));
    bf16* K16  = (bf16*)(ws + (32u << 20));
    bf16* Vt16 = (bf16*)(ws + (40u << 20));
    unsigned long long* Mb = (unsigned long long*)(ws + (48u << 20));

    ConvArgs ca;
    ca.src[0] = X_to;   ca.dst[0] = Xt16; ca.nvec[0] = MROWS * DIM / 4;
    ca.src[1] = X_from; ca.dst[1] = Xf16; ca.nvec[1] = MROWS * DIM / 4;
    ca.src[2] = Wq;     ca.dst[2] = Wq16; ca.nvec[2] = DIM * DIM / 4;
    ca.src[3] = Wv;     ca.dst[3] = Wv16; ca.nvec[3] = DIM * DIM / 4;
    ca.src[4] = Wk;     ca.dst[4] = Wk16; ca.nvec[4] = DIM * DIM / 4;
    ca.src[5] = Wo;     ca.dst[5] = Wo16; ca.nvec[5] = DIM * DIM / 4;
    int cum = 0;
    for (int k = 0; k < 6; ++k) { cum += ca.nvec[k] / 256; ca.blk_end[k] = cum; }
    ca.mask = mask; ca.Mb = Mb;
    convert_pack<<<cum + 1024, 256, 0, stream>>>(ca);

    QkvArgs qa;
    qa.A[0] = Xt16; qa.W[0] = Wq16; qa.bias[0] = bq; qa.C[0] = Q16;
    qa.N[0] = DIM; qa.biasRow[0] = 0;
    qa.A[1] = Xf16; qa.W[1] = Wv16; qa.bias[1] = bv; qa.C[1] = K16;
    qa.N[1] = DIM; qa.biasRow[1] = 0;
    qa.A[2] = Wk16; qa.W[2] = Xf16; qa.bias[2] = bk; qa.C[2] = Vt16;
    qa.N[2] = MROWS; qa.biasRow[2] = 1;
    gemm_qkv<<<dim3(8, 32, 3), 256, 0, stream>>>(qa);

    attn_kernel<<<dim3(TT / 64, NH, BB), 256, 0, stream>>>(
        Q16, K16, Vt16, Mb, Q16);

    gemm_o<<<dim3(DIM / 64, MROWS / 128), 256, 0, stream>>>(Q16, Wo16, bo, out);
}

// Round 6
// 230.027 us; speedup vs baseline: 1.0444x; 1.0444x over previous
//
#include <hip/hip_runtime.h>
#include <hip/hip_bf16.h>
#include <math.h>

#define BB 4
#define TT 1024
#define FF 1024
#define DIM 1024
#define NH 16
#define HD 64
#define MROWS (BB * TT)   // 4096
#define FB (FF / 64)      // 16 uint64 mask words per row

typedef __attribute__((ext_vector_type(8))) short short8;
typedef __attribute__((ext_vector_type(4))) short short4v;
typedef __attribute__((ext_vector_type(4))) float f32x4;
typedef __hip_bfloat16 bf16;

__device__ __forceinline__ void async_copy16(const void* g, void* l) {
    __builtin_amdgcn_global_load_lds((const __attribute__((address_space(1))) void*)g,
                                     (__attribute__((address_space(3))) void*)l,
                                     16, 0, 0);
}

// ---------------------------------------------------------------------------
// Fused f32->bf16 convert (segments 0..5) + mask bit-pack (tail blocks).
// ---------------------------------------------------------------------------
struct ConvArgs {
    const float* src[6];
    bf16* dst[6];
    int nvec[6];
    int blk_end[6];
    const int* mask;
    unsigned long long* Mb;
};

__global__ __launch_bounds__(256) void convert_pack(ConvArgs a) {
    int bx = blockIdx.x;
    if (bx >= a.blk_end[5]) {
        const int lane = threadIdx.x & 63;
        const int waveId = (bx - a.blk_end[5]) * 4 + (threadIdx.x >> 6);
#pragma unroll
        for (int it = 0; it < 16; ++it) {
            int c = waveId * 16 + it;
            int v = a.mask[(size_t)c * 64 + lane];
            unsigned long long bits = __ballot(v != 0);
            if (lane == 0) a.Mb[c] = bits;
        }
        return;
    }
    int seg = 0;
#pragma unroll
    for (int k = 0; k < 5; ++k) if (bx >= a.blk_end[k]) seg = k + 1;
    int b0 = seg ? a.blk_end[seg - 1] : 0;
    int idx = (bx - b0) * 256 + threadIdx.x;
    if (idx >= a.nvec[seg]) return;
    float4 v = ((const float4*)a.src[seg])[idx];
    union { bf16 t[4]; ushort4 u; } o;
    o.t[0] = __float2bfloat16(v.x);
    o.t[1] = __float2bfloat16(v.y);
    o.t[2] = __float2bfloat16(v.z);
    o.t[3] = __float2bfloat16(v.w);
    *(ushort4*)(a.dst[seg] + 4 * (size_t)idx) = o.u;
}

// ---------------------------------------------------------------------------
// Fused Q/K/Vt projection GEMMs. grid (8,32,3). 128x128 tile, BK=64.
// XCD-aware block remap (unchanged from R5).
// ---------------------------------------------------------------------------
#define BK 64

struct QkvArgs {
    const bf16* A[3]; const bf16* W[3]; const float* bias[3]; bf16* C[3];
    int N[3]; int biasRow[3];
};

__global__ __launch_bounds__(256) void gemm_qkv(QkvArgs q) {
    __shared__ bf16 smem[128 * 132];
    bf16* As = smem;
    bf16* Bs = smem + 128 * BK;

    const int op = blockIdx.z;
    const bf16* A = q.A[op];
    const bf16* W = q.W[op];
    const float* bias = q.bias[op];
    bf16* C = q.C[op];
    const int N = q.N[op];
    const int brow = q.biasRow[op];

    const int lin = blockIdx.x + 8 * blockIdx.y;
    const int xcd = lin & 7;
    const int t   = lin >> 3;
    int m0, n0;
    if (brow) {
        m0 = (((t & 7) + xcd) & 7) * 128;
        n0 = (xcd * 4 + (t >> 3)) * 128;
    } else {
        m0 = (xcd * 4 + (t >> 3)) * 128;
        n0 = (((t & 7) + xcd) & 7) * 128;
    }

    const int tid  = threadIdx.x;
    const int lane = tid & 63;
    const int wave = tid >> 6;
    const int quad = lane >> 4;
    const int l16  = lane & 15;
    const int wm = wave & 1;
    const int wn = wave >> 1;
    const int wbase = tid & ~63;

    f32x4 acc[4][4] = {};

    for (int k0 = 0; k0 < DIM; k0 += BK) {
#pragma unroll
        for (int j = 0; j < 4; ++j) {
            int slot = j * 256 + tid;
            int r = slot >> 3;
            int g = (slot & 7) ^ (r & 7);
            async_copy16(A + (size_t)(m0 + r) * DIM + k0 + g * 8,
                         As + (size_t)(j * 256 + wbase) * 8);
            async_copy16(W + (size_t)(n0 + r) * DIM + k0 + g * 8,
                         Bs + (size_t)(j * 256 + wbase) * 8);
        }
        __syncthreads();

#pragma unroll
        for (int kk = 0; kk < 2; ++kk) {
            short8 a[4], b[4];
#pragma unroll
            for (int mi = 0; mi < 4; ++mi) {
                int r = wm * 64 + mi * 16 + l16;
                int p = (kk * 4 + quad) ^ (r & 7);
                a[mi] = *(const short8*)(As + r * BK + p * 8);
            }
#pragma unroll
            for (int ni = 0; ni < 4; ++ni) {
                int r = wn * 64 + ni * 16 + l16;
                int p = (kk * 4 + quad) ^ (r & 7);
                b[ni] = *(const short8*)(Bs + r * BK + p * 8);
            }
#pragma unroll
            for (int mi = 0; mi < 4; ++mi)
#pragma unroll
                for (int ni = 0; ni < 4; ++ni)
                    acc[mi][ni] = __builtin_amdgcn_mfma_f32_16x16x32_bf16(
                        a[mi], b[ni], acc[mi][ni], 0, 0, 0);
        }
        __syncthreads();
    }

    bf16* Cs = smem;
#pragma unroll
    for (int ni = 0; ni < 4; ++ni) {
        const int nl = wn * 64 + ni * 16 + l16;
        float bcol = brow ? 0.0f : bias[n0 + nl];
#pragma unroll
        for (int mi = 0; mi < 4; ++mi)
#pragma unroll
            for (int i = 0; i < 4; ++i) {
                const int ml = wm * 64 + mi * 16 + quad * 4 + i;
                float v = acc[mi][ni][i] + (brow ? bias[m0 + ml] : bcol);
                Cs[ml * 132 + nl] = __float2bfloat16(v);
            }
    }
    __syncthreads();
#pragma unroll
    for (int j = 0; j < 8; ++j) {
        int slot = j * 256 + tid;
        int rr = slot >> 4, cc = slot & 15;
        short8 v = *(const short8*)(Cs + rr * 132 + cc * 8);
        *(short8*)(C + (size_t)(m0 + rr) * N + n0 + cc * 8) = v;
    }
}

// ---------------------------------------------------------------------------
// O-projection GEMM (unchanged from R5).
// ---------------------------------------------------------------------------
__global__ __launch_bounds__(256) void gemm_o(
    const bf16* __restrict__ A, const bf16* __restrict__ W,
    const float* __restrict__ bias, float* __restrict__ C)
{
    __shared__ float smemf[128 * 66];
    bf16* As = (bf16*)smemf;
    bf16* Bs = As + 128 * BK;

    const int lin = blockIdx.x + 16 * blockIdx.y;
    const int xcd = lin & 7;
    const int t   = lin >> 3;
    const int m0 = (xcd * 4 + (t >> 4)) * 128;
    const int n0 = (((t & 15) + 2 * xcd) & 15) * 64;

    const int tid  = threadIdx.x;
    const int lane = tid & 63;
    const int wave = tid >> 6;
    const int quad = lane >> 4;
    const int l16  = lane & 15;
    const int wm = wave & 1;
    const int wn = wave >> 1;
    const int wbase = tid & ~63;

    f32x4 acc[4][2] = {};

    for (int k0 = 0; k0 < DIM; k0 += BK) {
#pragma unroll
        for (int j = 0; j < 4; ++j) {
            int slot = j * 256 + tid;
            int r = slot >> 3;
            int g = (slot & 7) ^ (r & 7);
            async_copy16(A + (size_t)(m0 + r) * DIM + k0 + g * 8,
                         As + (size_t)(j * 256 + wbase) * 8);
        }
#pragma unroll
        for (int j = 0; j < 2; ++j) {
            int slot = j * 256 + tid;
            int r = slot >> 3;
            int g = (slot & 7) ^ (r & 7);
            async_copy16(W + (size_t)(n0 + r) * DIM + k0 + g * 8,
                         Bs + (size_t)(j * 256 + wbase) * 8);
        }
        __syncthreads();

#pragma unroll
        for (int kk = 0; kk < 2; ++kk) {
            short8 a[4], b[2];
#pragma unroll
            for (int mi = 0; mi < 4; ++mi) {
                int r = wm * 64 + mi * 16 + l16;
                int p = (kk * 4 + quad) ^ (r & 7);
                a[mi] = *(const short8*)(As + r * BK + p * 8);
            }
#pragma unroll
            for (int ni = 0; ni < 2; ++ni) {
                int r = wn * 32 + ni * 16 + l16;
                int p = (kk * 4 + quad) ^ (r & 7);
                b[ni] = *(const short8*)(Bs + r * BK + p * 8);
            }
#pragma unroll
            for (int mi = 0; mi < 4; ++mi)
#pragma unroll
                for (int ni = 0; ni < 2; ++ni)
                    acc[mi][ni] = __builtin_amdgcn_mfma_f32_16x16x32_bf16(
                        a[mi], b[ni], acc[mi][ni], 0, 0, 0);
        }
        __syncthreads();
    }

    float* Cs = smemf;
#pragma unroll
    for (int ni = 0; ni < 2; ++ni) {
        const int nl = wn * 32 + ni * 16 + l16;
        const float bcol = bias[n0 + nl];
#pragma unroll
        for (int mi = 0; mi < 4; ++mi)
#pragma unroll
            for (int i = 0; i < 4; ++i) {
                const int ml = wm * 64 + mi * 16 + quad * 4 + i;
                Cs[ml * 66 + nl] = acc[mi][ni][i] + bcol;
            }
    }
    __syncthreads();
#pragma unroll
    for (int j = 0; j < 8; ++j) {
        int slot = j * 256 + tid;
        int rr = slot >> 4, cc = slot & 15;
        float4 v = *(const float4*)(Cs + rr * 66 + cc * 4);
        *(float4*)(C + (size_t)(m0 + rr) * DIM + n0 + cc * 4) = v;
    }
}

// ---------------------------------------------------------------------------
// MFMA flash attention, S^T formulation.
// S^T tiles (A=K, B=Q) put 4 consecutive f per lane at fixed t=lane&15:
//   - P written as 8B vector ds_writes into Pt[t][f] (own-wave rows only)
//   - PV A-frags read back as b128 in exactly the needed layout
//   - mask words: 16 uint64 preloaded per lane (own row), zero VMEM in loop
//   - l-sum: one scalar per lane, 2 shuffles + tiny LDS transpose at end
// Grid (T/64, NH, BB), 4 waves, f-chunk 128, XCD remap. Og aliases Qg.
// ---------------------------------------------------------------------------
__global__ __launch_bounds__(256, 4) void attn_kernel(
    const bf16* Qg, const bf16* __restrict__ Kg, const bf16* __restrict__ Vtg,
    const unsigned long long* __restrict__ Mbits, bf16* Og)
{
    __shared__ bf16 Ks[128 * 64];    // [f][d], 8-chunk XOR swizzle
    __shared__ bf16 Vts[64 * 128];   // [d][f], 16-chunk XOR swizzle
    __shared__ bf16 Pt[64 * 136];    // [t][f], padded rows
    __shared__ float ls[64];         // l transpose

    const int tid  = threadIdx.x;
    const int lane = tid & 63;
    const int wave = tid >> 6;
    const int quad = lane >> 4;
    const int l16  = lane & 15;

    const int lin = blockIdx.x + 16 * (blockIdx.y + 16 * blockIdx.z);
    const int xcd = lin & 7;
    const int t   = lin >> 3;
    const int bh  = xcd * 8 + (t >> 4);
    const int b   = bh >> 4;
    const int h   = bh & 15;
    const int t0  = (t & 15) * 64;

    const size_t qrow0 = (size_t)b * TT + t0;
    const size_t krow0 = (size_t)b * FF;
    const int wbase = tid & ~63;

    // Q fragments (B-operand: n=t=l16, k=d=quad*8+j) direct from global
    const bf16* qptr = Qg + (qrow0 + wave * 16 + l16) * DIM + h * HD;
    short8 qb0 = *(const short8*)(qptr + quad * 8);
    short8 qb1 = *(const short8*)(qptr + 32 + quad * 8);

    // preload this lane's 16 mask words (row t = wave*16 + l16)
    const unsigned long long* mrow = Mbits + (qrow0 + wave * 16 + l16) * FB;
    unsigned long long mw[16];
#pragma unroll
    for (int w = 0; w < 16; ++w) mw[w] = mrow[w];

    float lsum = 0.f;
    f32x4 oacc[4] = {};

#pragma unroll
    for (int it = 0; it < 8; ++it) {
        const int f0 = it * 128;
        // stage K chunk 128x64 and Vt chunk 64x128
#pragma unroll
        for (int j = 0; j < 4; ++j) {
            int slot = j * 256 + tid;
            int rk = slot >> 3;
            int gk = (slot & 7) ^ (rk & 7);
            async_copy16(Kg + (krow0 + f0 + rk) * DIM + h * HD + gk * 8,
                         Ks + (size_t)(j * 256 + wbase) * 8);
            int rv = slot >> 4;
            int gv = (slot & 15) ^ (rv & 15);
            async_copy16(Vtg + (size_t)(h * HD + rv) * MROWS + b * FF + f0 + gv * 8,
                         Vts + (size_t)(j * 256 + wbase) * 8);
        }
        __syncthreads();

        // S^T = K @ Q^T : 128 f-rows x 16 t-cols per wave (A=K, B=Q)
        f32x4 sacc[8];
#pragma unroll
        for (int ft = 0; ft < 8; ++ft) {
            int r = ft * 16 + l16;
            short8 ka0 = *(const short8*)(Ks + r * 64 + ((quad       ^ (r & 7)) * 8));
            short8 ka1 = *(const short8*)(Ks + r * 64 + (((quad + 4) ^ (r & 7)) * 8));
            f32x4 s = {};
            s = __builtin_amdgcn_mfma_f32_16x16x32_bf16(ka0, qb0, s, 0, 0, 0);
            s = __builtin_amdgcn_mfma_f32_16x16x32_bf16(ka1, qb1, s, 0, 0, 0);
            sacc[ft] = s;
        }

        // exp + mask + vectorized P writes (lane: t=l16, f=ft*16+quad*4+i)
        const unsigned long long w0 = mw[2 * it];
        const unsigned long long w1 = mw[2 * it + 1];
#pragma unroll
        for (int ft = 0; ft < 8; ++ft) {
            const unsigned long long word = (ft < 4) ? w0 : w1;
            const unsigned bits4 =
                (unsigned)(word >> ((ft & 3) * 16 + quad * 4)) & 0xFu;
            union { short4v v; short s[4]; } pk;
            float psum = 0.f;
#pragma unroll
            for (int i = 0; i < 4; ++i) {
                float p = (bits4 >> i) & 1u ? __expf(sacc[ft][i] * 0.125f) : 0.f;
                psum += p;
                pk.s[i] = (short)__bfloat16_as_ushort(__float2bfloat16(p));
            }
            lsum += psum;
            *(short4v*)(Pt + l16 * 136 + wave * 0 + (wave * 16 + l16) * 0 +
                        (wave * 16 + l16) * 136 - l16 * 136 + ft * 16 + quad * 4) = pk.v;
        }

        // PV A-frags from own Pt rows (in-order same-wave LDS)
        short8 pa[4];
#pragma unroll
        for (int kf = 0; kf < 4; ++kf)
            pa[kf] = *(const short8*)(Pt + (wave * 16 + l16) * 136 + kf * 32 + quad * 8);
#pragma unroll
        for (int nt = 0; nt < 4; ++nt) {
            int rd = nt * 16 + l16;
#pragma unroll
            for (int kf = 0; kf < 4; ++kf) {
                int g = (kf * 4 + quad) ^ (rd & 15);
                short8 vb = *(const short8*)(Vts + rd * 128 + g * 8);
                oacc[nt] = __builtin_amdgcn_mfma_f32_16x16x32_bf16(pa[kf], vb, oacc[nt], 0, 0, 0);
            }
        }
        __syncthreads();   // protect Ks/Vts before next staging
    }

    // reduce l across quads (lanes sharing l16): xor 16, 32
    lsum += __shfl_xor(lsum, 16);
    lsum += __shfl_xor(lsum, 32);
    if (quad == 0) ls[wave * 16 + l16] = lsum;   // same-wave readback below

    // epilogue: normalize (l for t=quad*4+i via ls) + coalesced store via Pt
#pragma unroll
    for (int i = 0; i < 4; ++i) {
        float inv = 1.0f / ls[wave * 16 + quad * 4 + i];
        const int prow = wave * 16 + quad * 4 + i;
#pragma unroll
        for (int nt = 0; nt < 4; ++nt)
            Pt[prow * 136 + nt * 16 + l16] = __float2bfloat16(oacc[nt][i] * inv);
    }
    __syncthreads();
#pragma unroll
    for (int j = 0; j < 2; ++j) {
        int s = j * 256 + tid;
        int rr = s >> 3, off = (s & 7) * 8;
        short8 v = *(const short8*)(Pt + rr * 136 + off);
        *(short8*)(Og + (qrow0 + rr) * DIM + h * HD + off) = v;
    }
}

// ---------------------------------------------------------------------------
extern "C" void kernel_launch(void* const* d_in, const int* in_sizes, int n_in,
                              void* d_out, int out_size, void* d_ws, size_t ws_size,
                              hipStream_t stream) {
    const float* X_to   = (const float*)d_in[0];
    const float* X_from = (const float*)d_in[1];
    const int*   mask   = (const int*)  d_in[2];
    const float* Wq     = (const float*)d_in[3];
    const float* bq     = (const float*)d_in[4];
    const float* Wk     = (const float*)d_in[5];
    const float* bk     = (const float*)d_in[6];
    const float* Wv     = (const float*)d_in[7];
    const float* bv     = (const float*)d_in[8];
    const float* Wo     = (const float*)d_in[9];
    const float* bo     = (const float*)d_in[10];
    float* out = (float*)d_out;

    char* ws = (char*)d_ws;
    bf16* Xt16 = (bf16*)(ws);
    bf16* Xf16 = (bf16*)(ws + (8u  << 20));
    bf16* Wq16 = (bf16*)(ws + (16u << 20));
    bf16* Wv16 = (bf16*)(ws + (18u << 20));
    bf16* Wk16 = (bf16*)(ws + (20u << 20));
    bf16* Wo16 = (bf16*)(ws + (22u << 20));
    bf16* Q16  = (bf16*)(ws + (24u << 20));
    bf16* K16  = (bf16*)(ws + (32u << 20));
    bf16* Vt16 = (bf16*)(ws + (40u << 20));
    unsigned long long* Mb = (unsigned long long*)(ws + (48u << 20));

    ConvArgs ca;
    ca.src[0] = X_to;   ca.dst[0] = Xt16; ca.nvec[0] = MROWS * DIM / 4;
    ca.src[1] = X_from; ca.dst[1] = Xf16; ca.nvec[1] = MROWS * DIM / 4;
    ca.src[2] = Wq;     ca.dst[2] = Wq16; ca.nvec[2] = DIM * DIM / 4;
    ca.src[3] = Wv;     ca.dst[3] = Wv16; ca.nvec[3] = DIM * DIM / 4;
    ca.src[4] = Wk;     ca.dst[4] = Wk16; ca.nvec[4] = DIM * DIM / 4;
    ca.src[5] = Wo;     ca.dst[5] = Wo16; ca.nvec[5] = DIM * DIM / 4;
    int cum = 0;
    for (int k = 0; k < 6; ++k) { cum += ca.nvec[k] / 256; ca.blk_end[k] = cum; }
    ca.mask = mask; ca.Mb = Mb;
    convert_pack<<<cum + 1024, 256, 0, stream>>>(ca);

    QkvArgs qa;
    qa.A[0] = Xt16; qa.W[0] = Wq16; qa.bias[0] = bq; qa.C[0] = Q16;
    qa.N[0] = DIM; qa.biasRow[0] = 0;
    qa.A[1] = Xf16; qa.W[1] = Wv16; qa.bias[1] = bv; qa.C[1] = K16;
    qa.N[1] = DIM; qa.biasRow[1] = 0;
    qa.A[2] = Wk16; qa.W[2] = Xf16; qa.bias[2] = bk; qa.C[2] = Vt16;
    qa.N[2] = MROWS; qa.biasRow[2] = 1;
    gemm_qkv<<<dim3(8, 32, 3), 256, 0, stream>>>(qa);

    attn_kernel<<<dim3(TT / 64, NH, BB), 256, 0, stream>>>(
        Q16, K16, Vt16, Mb, Q16);

    gemm_o<<<dim3(DIM / 64, MROWS / 128), 256, 0, stream>>>(Q16, Wo16, bo, out);
}

// Round 7
// 229.668 us; speedup vs baseline: 1.0461x; 1.0016x over previous
//
#include <hip/hip_runtime.h>
#include <hip/hip_bf16.h>
#include <math.h>

#define BB 4
#define TT 1024
#define FF 1024
#define DIM 1024
#define NH 16
#define HD 64
#define MROWS (BB * TT)   // 4096
#define FB (FF / 64)      // 16 uint64 mask words per row

typedef __attribute__((ext_vector_type(8))) short short8;
typedef __attribute__((ext_vector_type(4))) short short4v;
typedef __attribute__((ext_vector_type(4))) float f32x4;
typedef __hip_bfloat16 bf16;

__device__ __forceinline__ void async_copy16(const void* g, void* l) {
    __builtin_amdgcn_global_load_lds((const __attribute__((address_space(1))) void*)g,
                                     (__attribute__((address_space(3))) void*)l,
                                     16, 0, 0);
}

// ---------------------------------------------------------------------------
// Fused f32->bf16 convert (segments 0..5) + mask bit-pack (tail blocks).
// ---------------------------------------------------------------------------
struct ConvArgs {
    const float* src[6];
    bf16* dst[6];
    int nvec[6];
    int blk_end[6];
    const int* mask;
    unsigned long long* Mb;
};

__global__ __launch_bounds__(256) void convert_pack(ConvArgs a) {
    int bx = blockIdx.x;
    if (bx >= a.blk_end[5]) {
        const int lane = threadIdx.x & 63;
        const int waveId = (bx - a.blk_end[5]) * 4 + (threadIdx.x >> 6);
#pragma unroll
        for (int it = 0; it < 16; ++it) {
            int c = waveId * 16 + it;
            int v = a.mask[(size_t)c * 64 + lane];
            unsigned long long bits = __ballot(v != 0);
            if (lane == 0) a.Mb[c] = bits;
        }
        return;
    }
    int seg = 0;
#pragma unroll
    for (int k = 0; k < 5; ++k) if (bx >= a.blk_end[k]) seg = k + 1;
    int b0 = seg ? a.blk_end[seg - 1] : 0;
    int idx = (bx - b0) * 256 + threadIdx.x;
    if (idx >= a.nvec[seg]) return;
    float4 v = ((const float4*)a.src[seg])[idx];
    union { bf16 t[4]; ushort4 u; } o;
    o.t[0] = __float2bfloat16(v.x);
    o.t[1] = __float2bfloat16(v.y);
    o.t[2] = __float2bfloat16(v.z);
    o.t[3] = __float2bfloat16(v.w);
    *(ushort4*)(a.dst[seg] + 4 * (size_t)idx) = o.u;
}

// ---------------------------------------------------------------------------
// Fused Q/K/Vt projection GEMMs. grid (8,32,3). 128x128 tile, BK=64.
// XCD-aware block remap (unchanged).
// ---------------------------------------------------------------------------
#define BK 64

struct QkvArgs {
    const bf16* A[3]; const bf16* W[3]; const float* bias[3]; bf16* C[3];
    int N[3]; int biasRow[3];
};

__global__ __launch_bounds__(256) void gemm_qkv(QkvArgs q) {
    __shared__ bf16 smem[128 * 132];
    bf16* As = smem;
    bf16* Bs = smem + 128 * BK;

    const int op = blockIdx.z;
    const bf16* A = q.A[op];
    const bf16* W = q.W[op];
    const float* bias = q.bias[op];
    bf16* C = q.C[op];
    const int N = q.N[op];
    const int brow = q.biasRow[op];

    const int lin = blockIdx.x + 8 * blockIdx.y;
    const int xcd = lin & 7;
    const int t   = lin >> 3;
    int m0, n0;
    if (brow) {
        m0 = (((t & 7) + xcd) & 7) * 128;
        n0 = (xcd * 4 + (t >> 3)) * 128;
    } else {
        m0 = (xcd * 4 + (t >> 3)) * 128;
        n0 = (((t & 7) + xcd) & 7) * 128;
    }

    const int tid  = threadIdx.x;
    const int lane = tid & 63;
    const int wave = tid >> 6;
    const int quad = lane >> 4;
    const int l16  = lane & 15;
    const int wm = wave & 1;
    const int wn = wave >> 1;
    const int wbase = tid & ~63;

    f32x4 acc[4][4] = {};

    for (int k0 = 0; k0 < DIM; k0 += BK) {
#pragma unroll
        for (int j = 0; j < 4; ++j) {
            int slot = j * 256 + tid;
            int r = slot >> 3;
            int g = (slot & 7) ^ (r & 7);
            async_copy16(A + (size_t)(m0 + r) * DIM + k0 + g * 8,
                         As + (size_t)(j * 256 + wbase) * 8);
            async_copy16(W + (size_t)(n0 + r) * DIM + k0 + g * 8,
                         Bs + (size_t)(j * 256 + wbase) * 8);
        }
        __syncthreads();

#pragma unroll
        for (int kk = 0; kk < 2; ++kk) {
            short8 a[4], b[4];
#pragma unroll
            for (int mi = 0; mi < 4; ++mi) {
                int r = wm * 64 + mi * 16 + l16;
                int p = (kk * 4 + quad) ^ (r & 7);
                a[mi] = *(const short8*)(As + r * BK + p * 8);
            }
#pragma unroll
            for (int ni = 0; ni < 4; ++ni) {
                int r = wn * 64 + ni * 16 + l16;
                int p = (kk * 4 + quad) ^ (r & 7);
                b[ni] = *(const short8*)(Bs + r * BK + p * 8);
            }
#pragma unroll
            for (int mi = 0; mi < 4; ++mi)
#pragma unroll
                for (int ni = 0; ni < 4; ++ni)
                    acc[mi][ni] = __builtin_amdgcn_mfma_f32_16x16x32_bf16(
                        a[mi], b[ni], acc[mi][ni], 0, 0, 0);
        }
        __syncthreads();
    }

    bf16* Cs = smem;
#pragma unroll
    for (int ni = 0; ni < 4; ++ni) {
        const int nl = wn * 64 + ni * 16 + l16;
        float bcol = brow ? 0.0f : bias[n0 + nl];
#pragma unroll
        for (int mi = 0; mi < 4; ++mi)
#pragma unroll
            for (int i = 0; i < 4; ++i) {
                const int ml = wm * 64 + mi * 16 + quad * 4 + i;
                float v = acc[mi][ni][i] + (brow ? bias[m0 + ml] : bcol);
                Cs[ml * 132 + nl] = __float2bfloat16(v);
            }
    }
    __syncthreads();
#pragma unroll
    for (int j = 0; j < 8; ++j) {
        int slot = j * 256 + tid;
        int rr = slot >> 4, cc = slot & 15;
        short8 v = *(const short8*)(Cs + rr * 132 + cc * 8);
        *(short8*)(C + (size_t)(m0 + rr) * N + n0 + cc * 8) = v;
    }
}

// ---------------------------------------------------------------------------
// O-projection GEMM (unchanged).
// ---------------------------------------------------------------------------
__global__ __launch_bounds__(256) void gemm_o(
    const bf16* __restrict__ A, const bf16* __restrict__ W,
    const float* __restrict__ bias, float* __restrict__ C)
{
    __shared__ float smemf[128 * 66];
    bf16* As = (bf16*)smemf;
    bf16* Bs = As + 128 * BK;

    const int lin = blockIdx.x + 16 * blockIdx.y;
    const int xcd = lin & 7;
    const int t   = lin >> 3;
    const int m0 = (xcd * 4 + (t >> 4)) * 128;
    const int n0 = (((t & 15) + 2 * xcd) & 15) * 64;

    const int tid  = threadIdx.x;
    const int lane = tid & 63;
    const int wave = tid >> 6;
    const int quad = lane >> 4;
    const int l16  = lane & 15;
    const int wm = wave & 1;
    const int wn = wave >> 1;
    const int wbase = tid & ~63;

    f32x4 acc[4][2] = {};

    for (int k0 = 0; k0 < DIM; k0 += BK) {
#pragma unroll
        for (int j = 0; j < 4; ++j) {
            int slot = j * 256 + tid;
            int r = slot >> 3;
            int g = (slot & 7) ^ (r & 7);
            async_copy16(A + (size_t)(m0 + r) * DIM + k0 + g * 8,
                         As + (size_t)(j * 256 + wbase) * 8);
        }
#pragma unroll
        for (int j = 0; j < 2; ++j) {
            int slot = j * 256 + tid;
            int r = slot >> 3;
            int g = (slot & 7) ^ (r & 7);
            async_copy16(W + (size_t)(n0 + r) * DIM + k0 + g * 8,
                         Bs + (size_t)(j * 256 + wbase) * 8);
        }
        __syncthreads();

#pragma unroll
        for (int kk = 0; kk < 2; ++kk) {
            short8 a[4], b[2];
#pragma unroll
            for (int mi = 0; mi < 4; ++mi) {
                int r = wm * 64 + mi * 16 + l16;
                int p = (kk * 4 + quad) ^ (r & 7);
                a[mi] = *(const short8*)(As + r * BK + p * 8);
            }
#pragma unroll
            for (int ni = 0; ni < 2; ++ni) {
                int r = wn * 32 + ni * 16 + l16;
                int p = (kk * 4 + quad) ^ (r & 7);
                b[ni] = *(const short8*)(Bs + r * BK + p * 8);
            }
#pragma unroll
            for (int mi = 0; mi < 4; ++mi)
#pragma unroll
                for (int ni = 0; ni < 2; ++ni)
                    acc[mi][ni] = __builtin_amdgcn_mfma_f32_16x16x32_bf16(
                        a[mi], b[ni], acc[mi][ni], 0, 0, 0);
        }
        __syncthreads();
    }

    float* Cs = smemf;
#pragma unroll
    for (int ni = 0; ni < 2; ++ni) {
        const int nl = wn * 32 + ni * 16 + l16;
        const float bcol = bias[n0 + nl];
#pragma unroll
        for (int mi = 0; mi < 4; ++mi)
#pragma unroll
            for (int i = 0; i < 4; ++i) {
                const int ml = wm * 64 + mi * 16 + quad * 4 + i;
                Cs[ml * 66 + nl] = acc[mi][ni][i] + bcol;
            }
    }
    __syncthreads();
#pragma unroll
    for (int j = 0; j < 8; ++j) {
        int slot = j * 256 + tid;
        int rr = slot >> 4, cc = slot & 15;
        float4 v = *(const float4*)(Cs + rr * 66 + cc * 4);
        *(float4*)(C + (size_t)(m0 + rr) * DIM + n0 + cc * 4) = v;
    }
}

// ---------------------------------------------------------------------------
// MFMA flash attention, S^T formulation, NON-unrolled f-loop (I-cache
// resident body) + 2-register mask software prefetch.
// Lane owns t = wave*16 + l16 for S^T/P/l; 4 consecutive f per quad step.
// Grid (T/64, NH, BB), 4 waves, f-chunk 128, XCD remap. Og aliases Qg.
// ---------------------------------------------------------------------------
__global__ __launch_bounds__(256, 4) void attn_kernel(
    const bf16* Qg, const bf16* __restrict__ Kg, const bf16* __restrict__ Vtg,
    const unsigned long long* __restrict__ Mbits, bf16* Og)
{
    __shared__ bf16 Ks[128 * 64];    // [f][d], 8-chunk XOR swizzle
    __shared__ bf16 Vts[64 * 128];   // [d][f], 16-chunk XOR swizzle
    __shared__ bf16 Pt[64 * 136];    // [t][f], padded rows
    __shared__ float ls[64];         // l transpose

    const int tid  = threadIdx.x;
    const int lane = tid & 63;
    const int wave = tid >> 6;
    const int quad = lane >> 4;
    const int l16  = lane & 15;

    const int lin = blockIdx.x + 16 * (blockIdx.y + 16 * blockIdx.z);
    const int xcd = lin & 7;
    const int t   = lin >> 3;
    const int bh  = xcd * 8 + (t >> 4);
    const int b   = bh >> 4;
    const int h   = bh & 15;
    const int t0  = (t & 15) * 64;

    const size_t qrow0 = (size_t)b * TT + t0;
    const size_t krow0 = (size_t)b * FF;
    const int wbase = tid & ~63;
    const int myrow = wave * 16 + l16;   // this lane's t-row

    // Q fragments (B-operand: n=t=l16, k=d) direct from global
    const bf16* qptr = Qg + (qrow0 + myrow) * DIM + h * HD;
    short8 qb0 = *(const short8*)(qptr + quad * 8);
    short8 qb1 = *(const short8*)(qptr + 32 + quad * 8);

    // mask: this lane's row, 2 words per iteration, software prefetch
    const unsigned long long* mrow = Mbits + (qrow0 + myrow) * FB;
    unsigned long long w0 = mrow[0];
    unsigned long long w1 = mrow[1];

    float lsum = 0.f;
    f32x4 oacc[4] = {};

#pragma unroll 1
    for (int it = 0; it < 8; ++it) {
        const int f0 = it * 128;
        // stage K chunk 128x64 and Vt chunk 64x128
#pragma unroll
        for (int j = 0; j < 4; ++j) {
            int slot = j * 256 + tid;
            int rk = slot >> 3;
            int gk = (slot & 7) ^ (rk & 7);
            async_copy16(Kg + (krow0 + f0 + rk) * DIM + h * HD + gk * 8,
                         Ks + (size_t)(j * 256 + wbase) * 8);
            int rv = slot >> 4;
            int gv = (slot & 15) ^ (rv & 15);
            async_copy16(Vtg + (size_t)(h * HD + rv) * MROWS + b * FF + f0 + gv * 8,
                         Vts + (size_t)(j * 256 + wbase) * 8);
        }
        // prefetch next iteration's mask words (hidden behind this iter)
        unsigned long long nw0 = 0, nw1 = 0;
        if (it < 7) { nw0 = mrow[2 * it + 2]; nw1 = mrow[2 * it + 3]; }
        __syncthreads();

        // S^T = K @ Q^T : 128 f-rows x 16 t-cols per wave (A=K, B=Q)
        f32x4 sacc[8];
#pragma unroll
        for (int ft = 0; ft < 8; ++ft) {
            int r = ft * 16 + l16;
            short8 ka0 = *(const short8*)(Ks + r * 64 + ((quad       ^ (r & 7)) * 8));
            short8 ka1 = *(const short8*)(Ks + r * 64 + (((quad + 4) ^ (r & 7)) * 8));
            f32x4 s = {};
            s = __builtin_amdgcn_mfma_f32_16x16x32_bf16(ka0, qb0, s, 0, 0, 0);
            s = __builtin_amdgcn_mfma_f32_16x16x32_bf16(ka1, qb1, s, 0, 0, 0);
            sacc[ft] = s;
        }

        // exp + mask + vectorized P writes (lane: t=myrow, f=ft*16+quad*4+i)
#pragma unroll
        for (int ft = 0; ft < 8; ++ft) {
            const unsigned long long word = (ft < 4) ? w0 : w1;
            const unsigned bits4 =
                (unsigned)(word >> ((ft & 3) * 16 + quad * 4)) & 0xFu;
            union { short4v v; short s[4]; } pk;
            float psum = 0.f;
#pragma unroll
            for (int i = 0; i < 4; ++i) {
                float p = (bits4 >> i) & 1u ? __expf(sacc[ft][i] * 0.125f) : 0.f;
                psum += p;
                pk.s[i] = (short)__bfloat16_as_ushort(__float2bfloat16(p));
            }
            lsum += psum;
            *(short4v*)(Pt + myrow * 136 + ft * 16 + quad * 4) = pk.v;
        }
        w0 = nw0; w1 = nw1;

        // PV A-frags from own Pt rows (in-order same-wave LDS)
        short8 pa[4];
#pragma unroll
        for (int kf = 0; kf < 4; ++kf)
            pa[kf] = *(const short8*)(Pt + myrow * 136 + kf * 32 + quad * 8);
#pragma unroll
        for (int nt = 0; nt < 4; ++nt) {
            int rd = nt * 16 + l16;
#pragma unroll
            for (int kf = 0; kf < 4; ++kf) {
                int g = (kf * 4 + quad) ^ (rd & 15);
                short8 vb = *(const short8*)(Vts + rd * 128 + g * 8);
                oacc[nt] = __builtin_amdgcn_mfma_f32_16x16x32_bf16(pa[kf], vb, oacc[nt], 0, 0, 0);
            }
        }
        __syncthreads();   // protect Ks/Vts before next staging
    }

    // reduce l across quads (lanes sharing l16)
    lsum += __shfl_xor(lsum, 16);
    lsum += __shfl_xor(lsum, 32);
    if (quad == 0) ls[myrow] = lsum;   // same-wave readback below

    // epilogue: normalize (l for t=quad*4+i via ls) + coalesced store via Pt
#pragma unroll
    for (int i = 0; i < 4; ++i) {
        float inv = 1.0f / ls[wave * 16 + quad * 4 + i];
        const int prow = wave * 16 + quad * 4 + i;
#pragma unroll
        for (int nt = 0; nt < 4; ++nt)
            Pt[prow * 136 + nt * 16 + l16] = __float2bfloat16(oacc[nt][i] * inv);
    }
    __syncthreads();
#pragma unroll
    for (int j = 0; j < 2; ++j) {
        int s = j * 256 + tid;
        int rr = s >> 3, off = (s & 7) * 8;
        short8 v = *(const short8*)(Pt + rr * 136 + off);
        *(short8*)(Og + (qrow0 + rr) * DIM + h * HD + off) = v;
    }
}

// ---------------------------------------------------------------------------
extern "C" void kernel_launch(void* const* d_in, const int* in_sizes, int n_in,
                              void* d_out, int out_size, void* d_ws, size_t ws_size,
                              hipStream_t stream) {
    const float* X_to   = (const float*)d_in[0];
    const float* X_from = (const float*)d_in[1];
    const int*   mask   = (const int*)  d_in[2];
    const float* Wq     = (const float*)d_in[3];
    const float* bq     = (const float*)d_in[4];
    const float* Wk     = (const float*)d_in[5];
    const float* bk     = (const float*)d_in[6];
    const float* Wv     = (const float*)d_in[7];
    const float* bv     = (const float*)d_in[8];
    const float* Wo     = (const float*)d_in[9];
    const float* bo     = (const float*)d_in[10];
    float* out = (float*)d_out;

    char* ws = (char*)d_ws;
    bf16* Xt16 = (bf16*)(ws);
    bf16* Xf16 = (bf16*)(ws + (8u  << 20));
    bf16* Wq16 = (bf16*)(ws + (16u << 20));
    bf16* Wv16 = (bf16*)(ws + (18u << 20));
    bf16* Wk16 = (bf16*)(ws + (20u << 20));
    bf16* Wo16 = (bf16*)(ws + (22u << 20));
    bf16* Q16  = (bf16*)(ws + (24u << 20));
    bf16* K16  = (bf16*)(ws + (32u << 20));
    bf16* Vt16 = (bf16*)(ws + (40u << 20));
    unsigned long long* Mb = (unsigned long long*)(ws + (48u << 20));

    ConvArgs ca;
    ca.src[0] = X_to;   ca.dst[0] = Xt16; ca.nvec[0] = MROWS * DIM / 4;
    ca.src[1] = X_from; ca.dst[1] = Xf16; ca.nvec[1] = MROWS * DIM / 4;
    ca.src[2] = Wq;     ca.dst[2] = Wq16; ca.nvec[2] = DIM * DIM / 4;
    ca.src[3] = Wv;     ca.dst[3] = Wv16; ca.nvec[3] = DIM * DIM / 4;
    ca.src[4] = Wk;     ca.dst[4] = Wk16; ca.nvec[4] = DIM * DIM / 4;
    ca.src[5] = Wo;     ca.dst[5] = Wo16; ca.nvec[5] = DIM * DIM / 4;
    int cum = 0;
    for (int k = 0; k < 6; ++k) { cum += ca.nvec[k] / 256; ca.blk_end[k] = cum; }
    ca.mask = mask; ca.Mb = Mb;
    convert_pack<<<cum + 1024, 256, 0, stream>>>(ca);

    QkvArgs qa;
    qa.A[0] = Xt16; qa.W[0] = Wq16; qa.bias[0] = bq; qa.C[0] = Q16;
    qa.N[0] = DIM; qa.biasRow[0] = 0;
    qa.A[1] = Xf16; qa.W[1] = Wv16; qa.bias[1] = bv; qa.C[1] = K16;
    qa.N[1] = DIM; qa.biasRow[1] = 0;
    qa.A[2] = Wk16; qa.W[2] = Xf16; qa.bias[2] = bk; qa.C[2] = Vt16;
    qa.N[2] = MROWS; qa.biasRow[2] = 1;
    gemm_qkv<<<dim3(8, 32, 3), 256, 0, stream>>>(qa);

    attn_kernel<<<dim3(TT / 64, NH, BB), 256, 0, stream>>>(
        Q16, K16, Vt16, Mb, Q16);

    gemm_o<<<dim3(DIM / 64, MROWS / 128), 256, 0, stream>>>(Q16, Wo16, bo, out);
}